// Round 4
// baseline (387.888 us; speedup 1.0000x reference)
//
#include <hip/hip_runtime.h>
#include <hip/hip_bf16.h>
#include <cstdint>
#include <cstddef>

// Problem dims
#define B_N   64
#define T_N   500
#define K_IN  1250
#define KP    1280          // K padded to multiple of 32 (zero-filled)
#define N_H   512
#define M_N   32000

// GEMM1 tiling: 128x128 tile, 4 waves (2x2), wave tile 64x64, BK=32, dbuf
#define BM 128
#define BN 128
#define BK 32
#define NT (KP / BK)        // 40

typedef __attribute__((ext_vector_type(8))) short bf16x8;  // 8 bf16 = 4 VGPRs
typedef __attribute__((ext_vector_type(4))) float f32x4;   // MFMA acc

#define DECAY_SR  0.9048374180359595732f   // exp(-1/10)
#define DECAY_REF 0.3678794411714423216f   // exp(-1)
#define THETA 10.0f

__device__ __forceinline__ unsigned short f2bf(float f) {
  __hip_bfloat16 h = __float2bfloat16(f);          // RNE, lowers to v_cvt
  return *reinterpret_cast<unsigned short*>(&h);
}
__device__ __forceinline__ uint32_t f2bf2(float a, float b) {
  float2 t; t.x = a; t.y = b;
  __hip_bfloat162 h = __float22bfloat162_rn(t);    // v_cvt_pk_bf16_f32
  return *reinterpret_cast<uint32_t*>(&h);
}
__device__ __forceinline__ float bf2f(unsigned short s) {
  union { uint32_t u; float f; } v; v.u = ((uint32_t)s) << 16; return v.f;
}

// ---------------------------------------------------------------------------
// Pre-pass: W1 (512x1250 fp32) -> W1b (512x1280 bf16, zero-padded tail).
// ---------------------------------------------------------------------------
__global__ __launch_bounds__(256) void w1cvt_kernel(const float* __restrict__ W1,
                                                    short* __restrict__ W1b) {
  int k = blockIdx.x * 256 + threadIdx.x;   // 0..1279
  int n = blockIdx.y;                        // 0..511
  float v = (k < K_IN) ? W1[(size_t)n * K_IN + k] : 0.f;
  W1b[(size_t)n * KP + k] = (short)f2bf(v);
}

// ---------------------------------------------------------------------------
// GEMM1: U1[m][n] = sum_k X[m][k] * W1[n][k]
// 1000 blocks (250 x 4), 256 thr (4 waves 2x2), tile 128x128, BK=32.
// Double-buffered LDS, ONE barrier per K-step (stage t+1 issued before
// compute t; __syncthreads drains vmcnt+lgkm once per tile).
// Swizzle: 16B slot' = slot ^ ((row>>1)&3)  -> 2-way (free) on all LDS ops.
// B staged by global_load_lds with pre-swizzled SOURCE (linear LDS dest);
// A reg-staged fp32->bf16 (pk cvt) with swizzled ds_write_b128.
// k-pairing: k = (lane>>4)*8 + elem, identical A and B (layout-agnostic).
// ---------------------------------------------------------------------------
__global__ __launch_bounds__(256) void gemm1_kernel(const float* __restrict__ X,
                                                    const short* __restrict__ W1b,
                                                    unsigned short* __restrict__ U1) {
  __shared__ short As[2][BM * BK];   // 2 x 8 KiB
  __shared__ short Bs[2][BN * BK];   // 2 x 8 KiB  (32 KiB total)
  const int tid  = threadIdx.x;
  const int bm   = blockIdx.x * BM;
  const int bn   = blockIdx.y * BN;
  const int w    = tid >> 6;
  const int lane = tid & 63;
  const int wr   = w >> 1;          // 0..1
  const int wc   = w & 1;           // 0..1
  const int lrow = lane & 15;
  const int lgrp = lane >> 4;

  f32x4 acc[4][4];
  #pragma unroll
  for (int i = 0; i < 4; ++i)
    #pragma unroll
    for (int j = 0; j < 4; ++j)
      acc[i][j] = (f32x4){0.f, 0.f, 0.f, 0.f};

  const int arow  = tid >> 2;        // 0..63  (rows arow, arow+64)
  const int aslot = tid & 3;
  const int bch0  = w * 2;           // wave handles chunks bch0, bch0+1
  const int brow  = lane >> 2;       // row within 16-row chunk
  const int bslp  = lane & 3;        // dest slot'

  auto stage = [&](int buf, int k0) {
    // ---- B: global->LDS DMA, source pre-swizzled, dest linear ----
    #pragma unroll
    for (int c = 0; c < 2; ++c) {
      int ch = bch0 + c;
      int n  = ch * 16 + brow;                   // local col 0..127
      int ss = bslp ^ ((n >> 1) & 3);            // source slot
      const short* src = W1b + (size_t)(bn + n) * KP + k0 + ss * 8;
      __builtin_amdgcn_global_load_lds(
          (const __attribute__((address_space(1))) void*)src,
          (__attribute__((address_space(3))) void*)&Bs[buf][ch * 512], 16, 0, 0);
    }
    // ---- A: fp32 load + pk-cvt + swizzled ds_write_b128 ----
    #pragma unroll
    for (int rr = 0; rr < 2; ++rr) {
      int row = arow + rr * 64;
      int gk  = k0 + aslot * 8;
      const float* s = X + (size_t)(bm + row) * K_IN + gk;
      float v0, v1, v2, v3, v4, v5, v6, v7;
      if (gk + 7 < K_IN) {          // rows are 8B-aligned (pitch 5000B)
        float2 x0 = *(const float2*)(s);
        float2 x1 = *(const float2*)(s + 2);
        float2 x2 = *(const float2*)(s + 4);
        float2 x3 = *(const float2*)(s + 6);
        v0 = x0.x; v1 = x0.y; v2 = x1.x; v3 = x1.y;
        v4 = x2.x; v5 = x2.y; v6 = x3.x; v7 = x3.y;
      } else {                      // k tail (only k0=1248 step)
        v0 = (gk + 0 < K_IN) ? s[0] : 0.f;
        v1 = (gk + 1 < K_IN) ? s[1] : 0.f;
        v2 = (gk + 2 < K_IN) ? s[2] : 0.f;
        v3 = (gk + 3 < K_IN) ? s[3] : 0.f;
        v4 = (gk + 4 < K_IN) ? s[4] : 0.f;
        v5 = (gk + 5 < K_IN) ? s[5] : 0.f;
        v6 = (gk + 6 < K_IN) ? s[6] : 0.f;
        v7 = (gk + 7 < K_IN) ? s[7] : 0.f;
      }
      uint4 pk;
      pk.x = f2bf2(v0, v1); pk.y = f2bf2(v2, v3);
      pk.z = f2bf2(v4, v5); pk.w = f2bf2(v6, v7);
      *(uint4*)&As[buf][row * BK + ((aslot ^ ((row >> 1) & 3)) * 8)] = pk;
    }
  };

  stage(0, 0);
  __syncthreads();
  int pb = 0;
  for (int t = 0; t < NT; ++t) {
    if (t + 1 < NT) stage(pb ^ 1, (t + 1) * BK);   // prefetch next tile
    bf16x8 af[4], bv[4];
    #pragma unroll
    for (int i = 0; i < 4; ++i) {
      int r = wr * 64 + i * 16 + lrow;
      af[i] = *(const bf16x8*)&As[pb][r * BK + ((lgrp ^ ((r >> 1) & 3)) * 8)];
    }
    #pragma unroll
    for (int j = 0; j < 4; ++j) {
      int r = wc * 64 + j * 16 + lrow;
      bv[j] = *(const bf16x8*)&Bs[pb][r * BK + ((lgrp ^ ((r >> 1) & 3)) * 8)];
    }
    #pragma unroll
    for (int i = 0; i < 4; ++i)
      #pragma unroll
      for (int j = 0; j < 4; ++j)
        acc[i][j] = __builtin_amdgcn_mfma_f32_16x16x32_bf16(af[i], bv[j], acc[i][j], 0, 0, 0);
    __syncthreads();                 // drains DMA (vmcnt) + ds ops once/tile
    pb ^= 1;
  }

  // ---- epilogue: C/D map col=lane&15, row=(lane>>4)*4+reg; U1 bf16 ----
  #pragma unroll
  for (int i = 0; i < 4; ++i) {
    int row0 = bm + wr * 64 + i * 16 + lgrp * 4;
    #pragma unroll
    for (int j = 0; j < 4; ++j) {
      int col = bn + wc * 64 + j * 16 + lrow;
      #pragma unroll
      for (int r = 0; r < 4; ++r)
        U1[(size_t)(row0 + r) * N_H + col] = f2bf(acc[i][j][r]);
    }
  }
}

// ---------------------------------------------------------------------------
// Scan1: per (b,h) chain over T (bf16 input); emits spike BITMASK via ballot.
// S1m layout: [b][t][8 x u64], bit h&63 of word h>>6.
// 256 blocks x 128 thr -> every CU active; one-batch-ahead prefetch.
// ---------------------------------------------------------------------------
__global__ __launch_bounds__(128) void scan1_kernel(const unsigned short* __restrict__ U1,
                                                    unsigned long long* __restrict__ S1m) {
  int idx  = blockIdx.x * 128 + threadIdx.x;  // b*512 + h
  int b    = idx >> 9, h = idx & 511;
  int lane = threadIdx.x & 63;
  const unsigned short* u = U1 + (size_t)b * T_N * N_H + h;
  unsigned long long* mout = S1m + (size_t)b * T_N * 8 + (h >> 6);
  float p = 0.f, r = 0.f;
  float bufA[10], bufB[10];

  auto load = [&](float* buf, int t0) {
    #pragma unroll
    for (int j = 0; j < 10; ++j) buf[j] = bf2f(u[(size_t)(t0 + j) * N_H]);
  };
  auto proc = [&](const float* buf, int t0) {
    #pragma unroll
    for (int j = 0; j < 10; ++j) {
      p = DECAY_SR * p + buf[j];
      float v = p + r;
      bool sp = (v >= THETA);
      r = DECAY_REF * (r - (sp ? 2.f * THETA : 0.f));
      unsigned long long bal = __ballot(sp);
      if (lane == 0) mout[(size_t)(t0 + j) * 8] = bal;
    }
  };

  load(bufA, 0);
  for (int g = 0; g < 25; ++g) {
    int ta = g * 20, tb = ta + 10;
    load(bufB, tb);
    proc(bufA, ta);
    if (g < 24) load(bufA, tb + 10);
    proc(bufB, tb);
  }
}

// ---------------------------------------------------------------------------
// GEMM2 from bitmask: U2[m][o] = sum_{h: spike} W2[o][h]. Wave per m-row.
// Coalesced: lane l reads byte l of the 64B mask row (bits h = l*8+j).
// ---------------------------------------------------------------------------
__global__ __launch_bounds__(256) void gemm2_kernel(const unsigned char* __restrict__ S1b,
                                                    const float* __restrict__ W2,
                                                    float* __restrict__ U2) {
  int m    = blockIdx.x * 4 + (threadIdx.x >> 6);
  int lane = threadIdx.x & 63;
  unsigned int byte = S1b[(size_t)m * 64 + lane];
  float a0 = 0.f, a1 = 0.f;
  #pragma unroll
  for (int j = 0; j < 8; ++j) {
    int h = lane * 8 + j;
    float sel = ((byte >> j) & 1u) ? 1.f : 0.f;
    a0 += sel * W2[h];
    a1 += sel * W2[N_H + h];
  }
  #pragma unroll
  for (int off = 32; off >= 1; off >>= 1) {
    a0 += __shfl_down(a0, off);
    a1 += __shfl_down(a1, off);
  }
  if (lane == 0) {
    U2[(size_t)m * 2]     = a0;
    U2[(size_t)m * 2 + 1] = a1;
  }
}

// ---------------------------------------------------------------------------
// Scan2: per-b block; stage u2[b] (500x2) in LDS, lanes 0/1 run the scans.
// ---------------------------------------------------------------------------
__global__ __launch_bounds__(128) void scan2_kernel(const float* __restrict__ U2,
                                                    float* __restrict__ OUT) {
  __shared__ float lu[T_N * 2];
  __shared__ float ls[T_N * 2];
  int b = blockIdx.x;
  const float* src = U2 + (size_t)b * T_N * 2;
  for (int i = threadIdx.x; i < T_N * 2; i += 128) lu[i] = src[i];
  __syncthreads();
  if (threadIdx.x < 2) {
    int o = threadIdx.x;
    float p = 0.f, r = 0.f;
    for (int t = 0; t < T_N; ++t) {
      p = DECAY_SR * p + lu[t * 2 + o];
      float v = p + r;
      float sp = (v >= THETA) ? 1.f : 0.f;
      r = DECAY_REF * (r - 2.f * THETA * sp);
      ls[t * 2 + o] = sp;
    }
  }
  __syncthreads();
  float* dst = OUT + (size_t)b * T_N * 2;
  for (int i = threadIdx.x; i < T_N * 2; i += 128) dst[i] = ls[i];
}

// ---------------------------------------------------------------------------
extern "C" void kernel_launch(void* const* d_in, const int* in_sizes, int n_in,
                              void* d_out, int out_size, void* d_ws, size_t ws_size,
                              hipStream_t stream) {
  const float* X  = (const float*)d_in[0];   // (64,500,1250)
  const float* W1 = (const float*)d_in[1];   // (512,1250)
  const float* W2 = (const float*)d_in[2];   // (2,512)
  float* OUT = (float*)d_out;                // (64,500,2)

  char* ws = (char*)d_ws;
  short*              W1b = (short*)ws;                             //  1,310,720 B
  unsigned short*     U1  = (unsigned short*)(ws + 1310720);        // 32,768,000 B
  unsigned long long* S1m = (unsigned long long*)(ws + 34078720);   //  2,048,000 B
  float*              U2  = (float*)(ws + 36126720);                //    256,000 B

  w1cvt_kernel<<<dim3(KP / 256, N_H), 256, 0, stream>>>(W1, W1b);
  gemm1_kernel<<<dim3(M_N / BM, N_H / BN), 256, 0, stream>>>(X, W1b, U1);
  scan1_kernel<<<dim3((B_N * N_H) / 128), 128, 0, stream>>>(U1, S1m);
  gemm2_kernel<<<dim3(M_N / 4), 256, 0, stream>>>((const unsigned char*)S1m, W2, U2);
  scan2_kernel<<<dim3(B_N), 128, 0, stream>>>(U2, OUT);
}

// Round 6
// 381.953 us; speedup vs baseline: 1.0155x; 1.0155x over previous
//
#include <hip/hip_runtime.h>
#include <hip/hip_bf16.h>
#include <cstdint>
#include <cstddef>

// Problem dims
#define B_N   64
#define T_N   500
#define K_IN  1250
#define KP    1280          // K padded to multiple of 32 (zero-filled)
#define N_H   512
#define M_N   32000

// GEMM1 tiling: 64 x 512 (full-N) tile, 4 waves (1x4), wave tile 64x128
#define BM 64
#define BK 32
#define NT (KP / BK)        // 40

typedef __attribute__((ext_vector_type(8))) short bf16x8;  // 8 bf16 = 4 VGPRs
typedef __attribute__((ext_vector_type(4))) float f32x4;   // MFMA acc

#define DECAY_SR  0.9048374180359595732f   // exp(-1/10)
#define DECAY_REF 0.3678794411714423216f   // exp(-1)
#define THETA 10.0f

__device__ __forceinline__ unsigned short f2bf(float f) {
  __hip_bfloat16 h = __float2bfloat16(f);          // RNE
  return *reinterpret_cast<unsigned short*>(&h);
}
__device__ __forceinline__ uint32_t f2bf2(float a, float b) {
  float2 t; t.x = a; t.y = b;
  __hip_bfloat162 h = __float22bfloat162_rn(t);    // v_cvt_pk_bf16_f32
  return *reinterpret_cast<uint32_t*>(&h);
}
__device__ __forceinline__ float bf2f(unsigned short s) {
  union { uint32_t u; float f; } v; v.u = ((uint32_t)s) << 16; return v.f;
}

// ---------------------------------------------------------------------------
// Pre-pass: W1 (512x1250 fp32) -> W1b (512x1280 bf16, zero-padded tail).
// ---------------------------------------------------------------------------
__global__ __launch_bounds__(256) void w1cvt_kernel(const float* __restrict__ W1,
                                                    short* __restrict__ W1b) {
  int k = blockIdx.x * 256 + threadIdx.x;   // 0..1279
  int n = blockIdx.y;                        // 0..511
  float v = (k < K_IN) ? W1[(size_t)n * K_IN + k] : 0.f;
  W1b[(size_t)n * KP + k] = (short)f2bf(v);
}

// ---------------------------------------------------------------------------
// GEMM1: U1[m][n] = sum_k X[m][k] * W1[n][k]
// 500 blocks (M/64), FULL-N tile 64x512 -> X fetched exactly once (no
// inter-block redundancy); W1b (1.25 MB) is L2-resident on every XCD.
// 256 thr = 4 waves (1x4), wave tile 64x128 (4x8 frags): 12 ds_read_b128 :
// 32 MFMA per K-step. Double-buffered LDS (72 KB -> 2 blocks/CU), ONE
// barrier per K-step. Swizzle: slot' = slot ^ ((row>>1)&3), both-sides.
// k-pairing: k = (lane>>4)*8 + elem, identical A and B (layout-agnostic).
// ---------------------------------------------------------------------------
__global__ __launch_bounds__(256) void gemm1_kernel(const float* __restrict__ X,
                                                    const short* __restrict__ W1b,
                                                    unsigned short* __restrict__ U1) {
  __shared__ short As[2][BM * BK];    // 2 x 4 KiB
  __shared__ short Bs[2][N_H * BK];   // 2 x 32 KiB
  const int tid  = threadIdx.x;
  const int bm   = blockIdx.x * BM;
  const int w    = tid >> 6;          // 0..3 -> col block w*128
  const int lane = tid & 63;
  const int lrow = lane & 15;
  const int lgrp = lane >> 4;
  const int lsw  = lgrp ^ ((lrow >> 1) & 3);   // fragment-read slot (row16-invariant)

  f32x4 acc[4][8];
  #pragma unroll
  for (int i = 0; i < 4; ++i)
    #pragma unroll
    for (int j = 0; j < 8; ++j)
      acc[i][j] = (f32x4){0.f, 0.f, 0.f, 0.f};

  const int arow  = tid >> 2;         // 0..63
  const int aslot = tid & 3;
  const int awofs = arow * BK + ((aslot ^ ((arow >> 1) & 3)) * 8);
  const int brow16 = lane >> 2;       // row within 16-row chunk
  const int bslp   = lane & 3;

  auto stage = [&](int buf, int k0) {
    // ---- B: 8 chunks/wave, global->LDS DMA, pre-swizzled source ----
    #pragma unroll
    for (int c = 0; c < 8; ++c) {
      int n  = w * 128 + c * 16 + brow16;        // 0..511
      int ss = bslp ^ ((n >> 1) & 3);
      const short* src = W1b + (size_t)n * KP + k0 + ss * 8;
      __builtin_amdgcn_global_load_lds(
          (const __attribute__((address_space(1))) void*)src,
          (__attribute__((address_space(3))) void*)&Bs[buf][(w * 128 + c * 16) * BK],
          16, 0, 0);
    }
    // ---- A: fp32 load + pk-cvt + swizzled ds_write_b128 ----
    {
      int gk = k0 + aslot * 8;
      const float* s = X + (size_t)(bm + arow) * K_IN + gk;
      float v0, v1, v2, v3, v4, v5, v6, v7;
      if (gk + 7 < K_IN) {            // rows 8B-aligned (pitch 5000 B)
        float2 x0 = *(const float2*)(s);
        float2 x1 = *(const float2*)(s + 2);
        float2 x2 = *(const float2*)(s + 4);
        float2 x3 = *(const float2*)(s + 6);
        v0 = x0.x; v1 = x0.y; v2 = x1.x; v3 = x1.y;
        v4 = x2.x; v5 = x2.y; v6 = x3.x; v7 = x3.y;
      } else {                        // tail K-step (k0=1248)
        v0 = (gk + 0 < K_IN) ? s[0] : 0.f;
        v1 = (gk + 1 < K_IN) ? s[1] : 0.f;
        v2 = (gk + 2 < K_IN) ? s[2] : 0.f;
        v3 = (gk + 3 < K_IN) ? s[3] : 0.f;
        v4 = (gk + 4 < K_IN) ? s[4] : 0.f;
        v5 = (gk + 5 < K_IN) ? s[5] : 0.f;
        v6 = (gk + 6 < K_IN) ? s[6] : 0.f;
        v7 = (gk + 7 < K_IN) ? s[7] : 0.f;
      }
      uint4 pk;
      pk.x = f2bf2(v0, v1); pk.y = f2bf2(v2, v3);
      pk.z = f2bf2(v4, v5); pk.w = f2bf2(v6, v7);
      *(uint4*)&As[buf][awofs] = pk;
    }
  };

  stage(0, 0);
  __syncthreads();
  int pb = 0;
  for (int t = 0; t < NT; ++t) {
    if (t + 1 < NT) stage(pb ^ 1, (t + 1) * BK);   // prefetch next tile
    bf16x8 af[4], bv[8];
    #pragma unroll
    for (int i = 0; i < 4; ++i)
      af[i] = *(const bf16x8*)&As[pb][(i * 16 + lrow) * BK + lsw * 8];
    #pragma unroll
    for (int j = 0; j < 8; ++j)
      bv[j] = *(const bf16x8*)&Bs[pb][(w * 128 + j * 16 + lrow) * BK + lsw * 8];
    #pragma unroll
    for (int i = 0; i < 4; ++i)
      #pragma unroll
      for (int j = 0; j < 8; ++j)
        acc[i][j] = __builtin_amdgcn_mfma_f32_16x16x32_bf16(af[i], bv[j], acc[i][j], 0, 0, 0);
    __syncthreads();                  // drains DMA (vmcnt) + ds ops once/tile
    pb ^= 1;
  }

  // ---- epilogue: C/D map col=lane&15, row=(lane>>4)*4+reg; U1 bf16 ----
  #pragma unroll
  for (int i = 0; i < 4; ++i) {
    int row0 = bm + i * 16 + lgrp * 4;
    #pragma unroll
    for (int j = 0; j < 8; ++j) {
      int col = w * 128 + j * 16 + lrow;
      #pragma unroll
      for (int r = 0; r < 4; ++r)
        U1[(size_t)(row0 + r) * N_H + col] = f2bf(acc[i][j][r]);
    }
  }
}

// ---------------------------------------------------------------------------
// Scan1: per (b,h) chain over T (bf16 input); emits spike BITMASK via ballot.
// S1m layout: [b][t][8 x u64], bit h&63 of word h>>6.
// ---------------------------------------------------------------------------
__global__ __launch_bounds__(128) void scan1_kernel(const unsigned short* __restrict__ U1,
                                                    unsigned long long* __restrict__ S1m) {
  int idx  = blockIdx.x * 128 + threadIdx.x;  // b*512 + h
  int b    = idx >> 9, h = idx & 511;
  int lane = threadIdx.x & 63;
  const unsigned short* u = U1 + (size_t)b * T_N * N_H + h;
  unsigned long long* mout = S1m + (size_t)b * T_N * 8 + (h >> 6);
  float p = 0.f, r = 0.f;
  float bufA[10], bufB[10];

  auto load = [&](float* buf, int t0) {
    #pragma unroll
    for (int j = 0; j < 10; ++j) buf[j] = bf2f(u[(size_t)(t0 + j) * N_H]);
  };
  auto proc = [&](const float* buf, int t0) {
    #pragma unroll
    for (int j = 0; j < 10; ++j) {
      p = DECAY_SR * p + buf[j];
      float v = p + r;
      bool sp = (v >= THETA);
      r = DECAY_REF * (r - (sp ? 2.f * THETA : 0.f));
      unsigned long long bal = __ballot(sp);
      if (lane == 0) mout[(size_t)(t0 + j) * 8] = bal;
    }
  };

  load(bufA, 0);
  for (int g = 0; g < 25; ++g) {
    int ta = g * 20, tb = ta + 10;
    load(bufB, tb);
    proc(bufA, ta);
    if (g < 24) load(bufA, tb + 10);
    proc(bufB, tb);
  }
}

// ---------------------------------------------------------------------------
// GEMM2 from bitmask: U2[m][o] = sum_{h: spike} W2[o][h]. Wave per m-row.
// ---------------------------------------------------------------------------
__global__ __launch_bounds__(256) void gemm2_kernel(const unsigned char* __restrict__ S1b,
                                                    const float* __restrict__ W2,
                                                    float* __restrict__ U2) {
  int m    = blockIdx.x * 4 + (threadIdx.x >> 6);
  int lane = threadIdx.x & 63;
  unsigned int byte = S1b[(size_t)m * 64 + lane];
  float a0 = 0.f, a1 = 0.f;
  #pragma unroll
  for (int j = 0; j < 8; ++j) {
    int h = lane * 8 + j;
    float sel = ((byte >> j) & 1u) ? 1.f : 0.f;
    a0 += sel * W2[h];
    a1 += sel * W2[N_H + h];
  }
  #pragma unroll
  for (int off = 32; off >= 1; off >>= 1) {
    a0 += __shfl_down(a0, off);
    a1 += __shfl_down(a1, off);
  }
  if (lane == 0) {
    U2[(size_t)m * 2]     = a0;
    U2[(size_t)m * 2 + 1] = a1;
  }
}

// ---------------------------------------------------------------------------
// Scan2: per-b block; stage u2[b] (500x2) in LDS, lanes 0/1 run the scans.
// ---------------------------------------------------------------------------
__global__ __launch_bounds__(128) void scan2_kernel(const float* __restrict__ U2,
                                                    float* __restrict__ OUT) {
  __shared__ float lu[T_N * 2];
  __shared__ float ls[T_N * 2];
  int b = blockIdx.x;
  const float* src = U2 + (size_t)b * T_N * 2;
  for (int i = threadIdx.x; i < T_N * 2; i += 128) lu[i] = src[i];
  __syncthreads();
  if (threadIdx.x < 2) {
    int o = threadIdx.x;
    float p = 0.f, r = 0.f;
    for (int t = 0; t < T_N; ++t) {
      p = DECAY_SR * p + lu[t * 2 + o];
      float v = p + r;
      float sp = (v >= THETA) ? 1.f : 0.f;
      r = DECAY_REF * (r - 2.f * THETA * sp);
      ls[t * 2 + o] = sp;
    }
  }
  __syncthreads();
  float* dst = OUT + (size_t)b * T_N * 2;
  for (int i = threadIdx.x; i < T_N * 2; i += 128) dst[i] = ls[i];
}

// ---------------------------------------------------------------------------
extern "C" void kernel_launch(void* const* d_in, const int* in_sizes, int n_in,
                              void* d_out, int out_size, void* d_ws, size_t ws_size,
                              hipStream_t stream) {
  const float* X  = (const float*)d_in[0];   // (64,500,1250)
  const float* W1 = (const float*)d_in[1];   // (512,1250)
  const float* W2 = (const float*)d_in[2];   // (2,512)
  float* OUT = (float*)d_out;                // (64,500,2)

  char* ws = (char*)d_ws;
  short*              W1b = (short*)ws;                             //  1,310,720 B
  unsigned short*     U1  = (unsigned short*)(ws + 1310720);        // 32,768,000 B
  unsigned long long* S1m = (unsigned long long*)(ws + 34078720);   //  2,048,000 B
  float*              U2  = (float*)(ws + 36126720);                //    256,000 B

  w1cvt_kernel<<<dim3(KP / 256, N_H), 256, 0, stream>>>(W1, W1b);
  gemm1_kernel<<<dim3(M_N / BM), 256, 0, stream>>>(X, W1b, U1);
  scan1_kernel<<<dim3((B_N * N_H) / 128), 128, 0, stream>>>(U1, S1m);
  gemm2_kernel<<<dim3(M_N / 4), 256, 0, stream>>>((const unsigned char*)S1m, W2, U2);
  scan2_kernel<<<dim3(B_N), 128, 0, stream>>>(U2, OUT);
}

// Round 7
// 362.939 us; speedup vs baseline: 1.0687x; 1.0524x over previous
//
#include <hip/hip_runtime.h>
#include <hip/hip_bf16.h>
#include <cstdint>
#include <cstddef>

// Problem dims
#define B_N   64
#define T_N   500
#define K_IN  1250
#define KP    1280          // K padded to multiple of 32
#define N_H   512
#define M_N   32000

// GEMM1 tiling: 128 x 256 tile, 4 waves (2x2), wave tile 64x128
#define BM 128
#define BN 256
#define BK 32
#define NT (KP / BK)        // 40
#define XROWB (KP / 8)      // 160 bytes of bits per row

typedef __attribute__((ext_vector_type(8))) short bf16x8;  // 8 bf16 = 4 VGPRs
typedef __attribute__((ext_vector_type(4))) float f32x4;   // MFMA acc

#define DECAY_SR  0.9048374180359595732f   // exp(-1/10)
#define DECAY_REF 0.3678794411714423216f   // exp(-1)
#define THETA 10.0f

__device__ __forceinline__ unsigned short f2bf(float f) {
  __hip_bfloat16 h = __float2bfloat16(f);          // RNE
  return *reinterpret_cast<unsigned short*>(&h);
}
__device__ __forceinline__ float bf2f(unsigned short s) {
  union { uint32_t u; float f; } v; v.u = ((uint32_t)s) << 16; return v.f;
}

// ---------------------------------------------------------------------------
// Pre-pass A: bitpack X (binary spikes) -> Xb [32000][160B].
// One wave per row; 20 x {coalesced float load, ballot, lane0 u64 store}.
// ---------------------------------------------------------------------------
__global__ __launch_bounds__(256) void xpack_kernel(const float* __restrict__ X,
                                                    unsigned long long* __restrict__ Xb64) {
  int gw   = (blockIdx.x * 256 + threadIdx.x) >> 6;   // 0..31999 = row
  int lane = threadIdx.x & 63;
  const float* xr = X + (size_t)gw * K_IN;
  unsigned long long* out = Xb64 + (size_t)gw * (XROWB / 8);
  #pragma unroll
  for (int wd = 0; wd < 20; ++wd) {
    int k = wd * 64 + lane;
    float v = (k < K_IN) ? xr[k] : 0.f;
    unsigned long long m = __ballot(v > 0.5f);
    if (lane == 0) out[wd] = m;
  }
}

// ---------------------------------------------------------------------------
// Pre-pass B: W1 (512x1250 fp32) -> W1b (512x1280 bf16, zero-padded tail).
// ---------------------------------------------------------------------------
__global__ __launch_bounds__(256) void w1cvt_kernel(const float* __restrict__ W1,
                                                    short* __restrict__ W1b) {
  int k = blockIdx.x * 256 + threadIdx.x;   // 0..1279
  int n = blockIdx.y;                        // 0..511
  float v = (k < K_IN) ? W1[(size_t)n * K_IN + k] : 0.f;
  W1b[(size_t)n * KP + k] = (short)f2bf(v);
}

// ---------------------------------------------------------------------------
// GEMM1: U1[m][n] = sum_k X[m][k] * W1[n][k]
// Grid (2 n-blocks fastest, 250 m-strips): the 2 blocks sharing an X strip
// dispatch adjacently (L2/L3 temporal locality). 256 thr = 4 waves (2x2),
// wave tile 64x128 (4x8 16x16x32 frags).
// A-operand from BITPACKED Xb: per frag, each lane loads ONE byte
// (L1/L2-resident, 20KB/block) and expands via a 4KB LDS LUT
// (byte -> 8 x bf16{0,1}) with one ds_read_b128. No A staging, no A LDS.
// B staged via global_load_lds dbuf, swizzle slot' = slot ^ ((row>>1)&3)
// (round-4/6 verified: SQ_LDS_BANK_CONFLICT = 0). One barrier per K-step.
// LDS = 2*16KB (B) + 4KB (LUT) = 36KB -> 3-4 blocks/CU.
// k-pairing: k = (lane>>4)*8 + elem, identical A and B (layout-agnostic).
// ---------------------------------------------------------------------------
__global__ __launch_bounds__(256) void gemm1_kernel(const unsigned char* __restrict__ Xb,
                                                    const short* __restrict__ W1b,
                                                    unsigned short* __restrict__ U1) {
  __shared__ short Bs[2][BN * BK];   // 2 x 16 KiB
  __shared__ short LUT[256 * 8];     // 4 KiB: entry b = 8 bf16 (bits of b)
  const int tid  = threadIdx.x;
  const int bn   = blockIdx.x * BN;   // n-block fastest
  const int bm   = blockIdx.y * BM;
  const int w    = tid >> 6;
  const int lane = tid & 63;
  const int wr   = w >> 1;            // m half (0..1)
  const int wc   = w & 1;             // n half (0..1)
  const int lrow = lane & 15;
  const int lgrp = lane >> 4;
  const int lsw  = lgrp ^ ((lrow >> 1) & 3);   // read slot (row16-invariant)

  // ---- build LUT (256 entries x 16B) ----
  {
    int b = tid;   // 0..255
    uint32_t w0 = ((b & 1)  ? 0x3F80u : 0u) | ((b & 2)  ? 0x3F800000u : 0u);
    uint32_t w1 = ((b & 4)  ? 0x3F80u : 0u) | ((b & 8)  ? 0x3F800000u : 0u);
    uint32_t w2 = ((b & 16) ? 0x3F80u : 0u) | ((b & 32) ? 0x3F800000u : 0u);
    uint32_t w3 = ((b & 64) ? 0x3F80u : 0u) | ((b & 128)? 0x3F800000u : 0u);
    uint4 q; q.x = w0; q.y = w1; q.z = w2; q.w = w3;
    *(uint4*)&LUT[b * 8] = q;
  }

  f32x4 acc[4][8];
  #pragma unroll
  for (int i = 0; i < 4; ++i)
    #pragma unroll
    for (int j = 0; j < 8; ++j)
      acc[i][j] = (f32x4){0.f, 0.f, 0.f, 0.f};

  const int brow16 = lane >> 2;       // row within 16-row chunk
  const int bslp   = lane & 3;        // dest slot'
  // per-lane byte base for A bits: row = bm + wr*64 + i*16 + lrow
  const unsigned char* xb0 = Xb + (size_t)(bm + wr * 64 + lrow) * XROWB + lgrp;

  auto stageB = [&](int buf, int k0) {
    #pragma unroll
    for (int c = 0; c < 4; ++c) {
      int ch = w * 4 + c;                        // 0..15
      int nl = ch * 16 + brow16;                 // local col 0..255
      int ss = bslp ^ ((nl >> 1) & 3);           // source slot
      const short* src = W1b + (size_t)(bn + nl) * KP + k0 + ss * 8;
      __builtin_amdgcn_global_load_lds(
          (const __attribute__((address_space(1))) void*)src,
          (__attribute__((address_space(3))) void*)&Bs[buf][ch * 16 * BK], 16, 0, 0);
    }
  };

  // prologue: stage tile 0, load A bytes for tile 0
  stageB(0, 0);
  unsigned char c0 = xb0[0];
  unsigned char c1 = xb0[16 * XROWB];
  unsigned char c2 = xb0[32 * XROWB];
  unsigned char c3 = xb0[48 * XROWB];
  __syncthreads();

  int pb = 0;
  for (int t = 0; t < NT; ++t) {
    unsigned char n0 = c0, n1 = c1, n2 = c2, n3 = c3;
    if (t + 1 < NT) {
      stageB(pb ^ 1, (t + 1) * BK);              // B DMA for next tile
      const unsigned char* xbn = xb0 + (t + 1) * 4;
      n0 = xbn[0];
      n1 = xbn[16 * XROWB];
      n2 = xbn[32 * XROWB];
      n3 = xbn[48 * XROWB];
    }
    // A frags via LUT (one ds_read_b128 each; byte 0 broadcasts)
    bf16x8 af[4];
    af[0] = *(const bf16x8*)&LUT[(int)c0 * 8];
    af[1] = *(const bf16x8*)&LUT[(int)c1 * 8];
    af[2] = *(const bf16x8*)&LUT[(int)c2 * 8];
    af[3] = *(const bf16x8*)&LUT[(int)c3 * 8];
    bf16x8 bv[8];
    #pragma unroll
    for (int j = 0; j < 8; ++j) {
      int r = wc * 128 + j * 16 + lrow;
      bv[j] = *(const bf16x8*)&Bs[pb][r * BK + lsw * 8];
    }
    #pragma unroll
    for (int i = 0; i < 4; ++i)
      #pragma unroll
      for (int j = 0; j < 8; ++j)
        acc[i][j] = __builtin_amdgcn_mfma_f32_16x16x32_bf16(af[i], bv[j], acc[i][j], 0, 0, 0);
    __syncthreads();                  // drains B DMA + LDS ops once/tile
    pb ^= 1;
    c0 = n0; c1 = n1; c2 = n2; c3 = n3;
  }

  // ---- epilogue: C/D map col=lane&15, row=(lane>>4)*4+reg; U1 bf16 ----
  #pragma unroll
  for (int i = 0; i < 4; ++i) {
    int row0 = bm + wr * 64 + i * 16 + lgrp * 4;
    #pragma unroll
    for (int j = 0; j < 8; ++j) {
      int col = bn + wc * 128 + j * 16 + lrow;
      #pragma unroll
      for (int r = 0; r < 4; ++r)
        U1[(size_t)(row0 + r) * N_H + col] = f2bf(acc[i][j][r]);
    }
  }
}

// ---------------------------------------------------------------------------
// Scan1: per (b,h) chain over T (bf16 input); emits spike BITMASK via ballot.
// S1m layout: [b][t][8 x u64], bit h&63 of word h>>6.
// ---------------------------------------------------------------------------
__global__ __launch_bounds__(128) void scan1_kernel(const unsigned short* __restrict__ U1,
                                                    unsigned long long* __restrict__ S1m) {
  int idx  = blockIdx.x * 128 + threadIdx.x;  // b*512 + h
  int b    = idx >> 9, h = idx & 511;
  int lane = threadIdx.x & 63;
  const unsigned short* u = U1 + (size_t)b * T_N * N_H + h;
  unsigned long long* mout = S1m + (size_t)b * T_N * 8 + (h >> 6);
  float p = 0.f, r = 0.f;
  float bufA[10], bufB[10];

  auto load = [&](float* buf, int t0) {
    #pragma unroll
    for (int j = 0; j < 10; ++j) buf[j] = bf2f(u[(size_t)(t0 + j) * N_H]);
  };
  auto proc = [&](const float* buf, int t0) {
    #pragma unroll
    for (int j = 0; j < 10; ++j) {
      p = DECAY_SR * p + buf[j];
      float v = p + r;
      bool sp = (v >= THETA);
      r = DECAY_REF * (r - (sp ? 2.f * THETA : 0.f));
      unsigned long long bal = __ballot(sp);
      if (lane == 0) mout[(size_t)(t0 + j) * 8] = bal;
    }
  };

  load(bufA, 0);
  for (int g = 0; g < 25; ++g) {
    int ta = g * 20, tb = ta + 10;
    load(bufB, tb);
    proc(bufA, ta);
    if (g < 24) load(bufA, tb + 10);
    proc(bufB, tb);
  }
}

// ---------------------------------------------------------------------------
// GEMM2 from bitmask: U2[m][o] = sum_{h: spike} W2[o][h]. Wave per m-row.
// ---------------------------------------------------------------------------
__global__ __launch_bounds__(256) void gemm2_kernel(const unsigned char* __restrict__ S1b,
                                                    const float* __restrict__ W2,
                                                    float* __restrict__ U2) {
  int m    = blockIdx.x * 4 + (threadIdx.x >> 6);
  int lane = threadIdx.x & 63;
  unsigned int byte = S1b[(size_t)m * 64 + lane];
  float a0 = 0.f, a1 = 0.f;
  #pragma unroll
  for (int j = 0; j < 8; ++j) {
    int h = lane * 8 + j;
    float sel = ((byte >> j) & 1u) ? 1.f : 0.f;
    a0 += sel * W2[h];
    a1 += sel * W2[N_H + h];
  }
  #pragma unroll
  for (int off = 32; off >= 1; off >>= 1) {
    a0 += __shfl_down(a0, off);
    a1 += __shfl_down(a1, off);
  }
  if (lane == 0) {
    U2[(size_t)m * 2]     = a0;
    U2[(size_t)m * 2 + 1] = a1;
  }
}

// ---------------------------------------------------------------------------
// Scan2: per-b block; stage u2[b] (500x2) in LDS, lanes 0/1 run the scans.
// ---------------------------------------------------------------------------
__global__ __launch_bounds__(128) void scan2_kernel(const float* __restrict__ U2,
                                                    float* __restrict__ OUT) {
  __shared__ float lu[T_N * 2];
  __shared__ float ls[T_N * 2];
  int b = blockIdx.x;
  const float* src = U2 + (size_t)b * T_N * 2;
  for (int i = threadIdx.x; i < T_N * 2; i += 128) lu[i] = src[i];
  __syncthreads();
  if (threadIdx.x < 2) {
    int o = threadIdx.x;
    float p = 0.f, r = 0.f;
    for (int t = 0; t < T_N; ++t) {
      p = DECAY_SR * p + lu[t * 2 + o];
      float v = p + r;
      float sp = (v >= THETA) ? 1.f : 0.f;
      r = DECAY_REF * (r - 2.f * THETA * sp);
      ls[t * 2 + o] = sp;
    }
  }
  __syncthreads();
  float* dst = OUT + (size_t)b * T_N * 2;
  for (int i = threadIdx.x; i < T_N * 2; i += 128) dst[i] = ls[i];
}

// ---------------------------------------------------------------------------
extern "C" void kernel_launch(void* const* d_in, const int* in_sizes, int n_in,
                              void* d_out, int out_size, void* d_ws, size_t ws_size,
                              hipStream_t stream) {
  const float* X  = (const float*)d_in[0];   // (64,500,1250)
  const float* W1 = (const float*)d_in[1];   // (512,1250)
  const float* W2 = (const float*)d_in[2];   // (2,512)
  float* OUT = (float*)d_out;                // (64,500,2)

  char* ws = (char*)d_ws;
  short*              W1b = (short*)ws;                             //  1,310,720 B
  unsigned short*     U1  = (unsigned short*)(ws + 1310720);        // 32,768,000 B
  unsigned long long* S1m = (unsigned long long*)(ws + 34078720);   //  2,048,000 B
  float*              U2  = (float*)(ws + 36126720);                //    256,000 B
  unsigned long long* Xb  = (unsigned long long*)(ws + 36382720);   //  5,120,000 B
                                                                    // total ~41.5 MB (round 1 used 98.5 MB OK)

  xpack_kernel<<<dim3(M_N / 4), 256, 0, stream>>>(X, Xb);
  w1cvt_kernel<<<dim3(KP / 256, N_H), 256, 0, stream>>>(W1, (short*)W1b);
  gemm1_kernel<<<dim3(N_H / BN, M_N / BM), 256, 0, stream>>>((const unsigned char*)Xb, W1b, U1);
  scan1_kernel<<<dim3((B_N * N_H) / 128), 128, 0, stream>>>(U1, S1m);
  gemm2_kernel<<<dim3(M_N / 4), 256, 0, stream>>>((const unsigned char*)S1m, W2, U2);
  scan2_kernel<<<dim3(B_N), 128, 0, stream>>>(U2, OUT);
}